// Round 16
// baseline (534.197 us; speedup 1.0000x reference)
//
#include <hip/hip_runtime.h>
#include <cstdint>

typedef unsigned int uint;
typedef unsigned short ushort_t;
typedef unsigned long long ull;
typedef __attribute__((ext_vector_type(8))) short bf16x8;
typedef __attribute__((ext_vector_type(4))) float f32x4;
typedef __attribute__((ext_vector_type(2))) float f32x2;

#define B_   16
#define N_   2048
#define S_   512
#define G_   8192       // B_*S_
#define DIN  64
#define DOUT 128
#define K_   32
#define ATS  136        // gemm2 actT row stride (bf16)

__device__ __forceinline__ uint bf16b(float f) {
  uint u = __float_as_uint(f);
  return (u + 0x7fffu + ((u >> 16) & 1u)) >> 16;
}
__device__ __forceinline__ float bf2f(uint b) { return __uint_as_float(b << 16); }

// u64 max with one DPP step applied to both halves (bc=1 zero-fill = identity for max)
template<int CTRL, int RM>
__device__ __forceinline__ ull dpp_max_step(ull x) {
  uint lo = (uint)x, hi = (uint)(x >> 32);
  uint nlo = (uint)__builtin_amdgcn_update_dpp((int)lo, (int)lo, CTRL, RM, 0xf, true);
  uint nhi = (uint)__builtin_amdgcn_update_dpp((int)hi, (int)hi, CTRL, RM, 0xf, true);
  ull y = ((ull)nhi << 32) | (ull)nlo;
  return x > y ? x : y;
}

// ---------------- front: fps (blocks 0-15) | txp (16-527) | prep (528-591) --------
// FPS: barrier-free spin-flag sync. Each wave's lane63 publishes
// {seq2|dist<<30|(2047-j)} via one volatile b64 LDS store; waves spin on the 4
// slots (double-buffered by s&1, seq = s&3, init seq=3). Consumption chain makes
// clobber/stale impossible; double-read guards b64 tearing; guard bounds the spin.
__global__ __launch_bounds__(256) void front_kernel(const float* __restrict__ coords,
    const float* __restrict__ x, const float* __restrict__ W1,
    const float* __restrict__ W2, int* __restrict__ fidx,
    float* __restrict__ out_xyz, ushort_t* __restrict__ xT,
    ushort_t* __restrict__ Bp1, ushort_t* __restrict__ Bpd,
    ushort_t* __restrict__ Bp2) {
  int blk = blockIdx.x;
  int tid = threadIdx.x;
  if (blk < 16) {
    int b = blk;
    const float* cb = coords + (size_t)b * (N_ * 3);
    __shared__ float sptx[N_], spty[N_], sptz[N_];
    __shared__ ull   skey[2][4];
    __shared__ int   sfar[S_];
    int lane = tid & 63, wid = tid >> 6;
    for (int j = tid; j < N_; j += 256) {
      sptx[j] = cb[3 * j]; spty[j] = cb[3 * j + 1]; sptz[j] = cb[3 * j + 2];
    }
    if (tid < 8) skey[tid >> 2][tid & 3] = (3ull << 62);   // invalid seq marker
    f32x2 px[4], py[4], pz[4], dist[4];
    uint nidx[8];
    int j0 = tid * 8;
#pragma unroll
    for (int p = 0; p < 4; ++p) {
      int j = j0 + 2 * p;
      px[p].x = cb[3 * j];     py[p].x = cb[3 * j + 1]; pz[p].x = cb[3 * j + 2];
      px[p].y = cb[3 * j + 3]; py[p].y = cb[3 * j + 4]; pz[p].y = cb[3 * j + 5];
      dist[p].x = 1e10f; dist[p].y = 1e10f;
      nidx[2 * p] = ~(uint)j; nidx[2 * p + 1] = ~(uint)(j + 1);
    }
    float cx = cb[0], cy = cb[1], cz = cb[2];
    uint far = 0;
    __syncthreads();
    for (int s = 0; s < S_; ++s) {
      if (tid == 0) sfar[s] = (int)far;          // PRE-update far (matches jax scan)
      f32x2 c2x = {cx, cx}, c2y = {cy, cy}, c2z = {cz, cz};
      ull best = 0;
#pragma unroll
      for (int p = 0; p < 4; ++p) {
        f32x2 dx, dy, dz, qx, qy, qz, s1, s2;
        asm("v_pk_add_f32 %0, %1, %2 neg_lo:[0,1] neg_hi:[0,1]" : "=v"(dx) : "v"(px[p]), "v"(c2x));
        asm("v_pk_add_f32 %0, %1, %2 neg_lo:[0,1] neg_hi:[0,1]" : "=v"(dy) : "v"(py[p]), "v"(c2y));
        asm("v_pk_add_f32 %0, %1, %2 neg_lo:[0,1] neg_hi:[0,1]" : "=v"(dz) : "v"(pz[p]), "v"(c2z));
        asm("v_pk_mul_f32 %0, %1, %1" : "=v"(qx) : "v"(dx));
        asm("v_pk_mul_f32 %0, %1, %1" : "=v"(qy) : "v"(dy));
        asm("v_pk_mul_f32 %0, %1, %1" : "=v"(qz) : "v"(dz));
        asm("v_pk_add_f32 %0, %1, %2" : "=v"(s1) : "v"(qx), "v"(qy));
        asm("v_pk_add_f32 %0, %1, %2" : "=v"(s2) : "v"(s1), "v"(qz));
        float n0 = fminf(dist[p].x, s2.x);
        float n1 = fminf(dist[p].y, s2.y);
        dist[p].x = n0; dist[p].y = n1;
        ull p0 = ((ull)__float_as_uint(n0) << 32) | (ull)nidx[2 * p];
        ull p1 = ((ull)__float_as_uint(n1) << 32) | (ull)nidx[2 * p + 1];
        best = best > p0 ? best : p0;
        best = best > p1 ? best : p1;
      }
      best = dpp_max_step<0x111, 0xf>(best);   // row_shr:1
      best = dpp_max_step<0x112, 0xf>(best);   // row_shr:2
      best = dpp_max_step<0x114, 0xf>(best);   // row_shr:4
      best = dpp_max_step<0x118, 0xf>(best);   // row_shr:8
      best = dpp_max_step<0x142, 0xa>(best);   // row_bcast:15 -> rows 1,3
      best = dpp_max_step<0x143, 0xc>(best);   // row_bcast:31 -> rows 2,3
      // slot value: [63:62]=seq, [60:30]=dist bits (<2^31 since d<=12), [10:0]=2047-j
      ull sq = (ull)(s & 3);
      ull slotval = (sq << 62) | ((best >> 32) << 30) | (best & 0x7FFull);
      int pb = s & 1;
      if (lane == 63) *(volatile ull*)&skey[pb][wid] = slotval;
      volatile ull* q0 = (volatile ull*)&skey[pb][0];
      volatile ull* q1 = (volatile ull*)&skey[pb][1];
      volatile ull* q2 = (volatile ull*)&skey[pb][2];
      volatile ull* q3 = (volatile ull*)&skey[pb][3];
      ull k0, k1, k2, k3;
      for (int guard = 0; guard < (1 << 20); ++guard) {
        k0 = *q0; k1 = *q1; k2 = *q2; k3 = *q3;
        if (((k0 >> 62) == sq) & ((k1 >> 62) == sq) & ((k2 >> 62) == sq) & ((k3 >> 62) == sq)) {
          ull r0 = *q0, r1 = *q1, r2 = *q2, r3 = *q3;   // tear guard: re-read stable
          if (r0 == k0 && r1 == k1 && r2 == k2 && r3 == k3) break;
        }
      }
      uint w0 = 2047u - (uint)(k0 & 0x7FFull), w1 = 2047u - (uint)(k1 & 0x7FFull);
      uint w2 = 2047u - (uint)(k2 & 0x7FFull), w3 = 2047u - (uint)(k3 & 0x7FFull);
      float x0 = sptx[w0], y0 = spty[w0], z0 = sptz[w0];   // 12 speculative broadcast
      float x1 = sptx[w1], y1 = spty[w1], z1 = sptz[w1];   // reads overlap the tree
      float x2 = sptx[w2], y2 = spty[w2], z2 = sptz[w2];
      float x3 = sptx[w3], y3 = spty[w3], z3 = sptz[w3];
      bool t01 = k0 > k1, t23 = k2 > k3;    // seq bits equal -> dist field dominates
      ull ka = t01 ? k0 : k1;  float xa = t01 ? x0 : x1, ya = t01 ? y0 : y1, za = t01 ? z0 : z1;
      ull kb = t23 ? k2 : k3;  float xb = t23 ? x2 : x3, yb = t23 ? y2 : y3, zb = t23 ? z2 : z3;
      bool tw = ka > kb;
      far = 2047u - (uint)((tw ? ka : kb) & 0x7FFull);
      cx = tw ? xa : xb; cy = tw ? ya : yb; cz = tw ? za : zb;
    }
    __syncthreads();
    for (int s2 = tid; s2 < S_; s2 += 256) {
      int f = sfar[s2];
      fidx[b * S_ + s2] = f;
      int o = (b * S_ + s2) * 3;
      out_xyz[o] = sptx[f]; out_xyz[o + 1] = spty[f]; out_xyz[o + 2] = sptz[f];
    }
  } else if (blk < 528) {
    // ------------------ txp: x[b][c][n] fp32 -> xT[b][n][c] bf16 ------------------
    __shared__ float tile[64][65];
    int blk2 = blk - 16;
    int b = blk2 >> 5;            // 16 b x 32 n-tiles
    int n0 = (blk2 & 31) * 64;
    int nn = tid & 63, c4 = tid >> 6;
    const float* xb = x + (size_t)b * (DIN * N_);
#pragma unroll
    for (int i = 0; i < 16; ++i) {
      int c = c4 * 16 + i;
      tile[nn][c] = xb[(size_t)c * N_ + n0 + nn];   // coalesced along n
    }
    __syncthreads();
#pragma unroll
    for (int i = 0; i < 16; ++i) {
      int n = c4 * 16 + i;
      xT[((size_t)b * N_ + n0 + n) * 64 + nn] = (ushort_t)bf16b(tile[n][nn]);  // coalesced along c
    }
  } else {
    // ------------------ prep: B-fragment packs for both GEMMs ------------------
    int i = (blk - 528) * 256 + tid;   // 16384
    int j2 = i & 7, l = (i >> 3) & 63;
    {
      int kc = (i >> 9) & 3, nt = i >> 11;
      int o2 = nt * 16 + (l & 15);
      int c2 = kc * 32 + ((l >> 4) * 8) + j2;
      Bp2[i] = (ushort_t)bf16b(W2[o2 * 128 + c2]);
    }
    if (i < 8192) {
      int kc = (i >> 9) & 1, nt = (i >> 10) & 7;
      int o2 = nt * 16 + (l & 15);
      int c2 = kc * 32 + ((l >> 4) * 8) + j2;
      float wa = W1[o2 * 128 + c2];
      float wb = W1[o2 * 128 + 64 + c2];
      Bp1[i] = (ushort_t)bf16b(wa);
      Bpd[i] = (ushort_t)bf16b(wb - wa);
    }
  }
}

// ---------------- GEMM1 (MFMA bf16) + inline ball query: stats only --------------
// o-major stats (R12-proven): psum[o*G+g].
__global__ __launch_bounds__(256) void gemm1_kernel(const ushort_t* __restrict__ xT,
    const float* __restrict__ coords, const int* __restrict__ fidx,
    const ushort_t* __restrict__ Bp1, const ushort_t* __restrict__ Bpd,
    int* __restrict__ gidx, float* __restrict__ psum, float* __restrict__ psq) {
  __shared__ int sgidx[4][K_];
  int tid = threadIdx.x;
  int lane = tid & 63, wid = tid >> 6;
  int g = __builtin_amdgcn_readfirstlane(blockIdx.x * 4 + wid);
  int b = g >> 9;
  const float* cb = coords + (size_t)b * (N_ * 3);
  int nf = fidx[g];
  {
    float cx = cb[3 * nf], cy = cb[3 * nf + 1], cz = cb[3 * nf + 2];
    int cnt = 0, first = 0;
    bool hasfirst = false;
    for (int base = 0; base < N_; base += 64) {
      int j = base + lane;
      float dx = __fsub_rn(cb[3 * j], cx);
      float dy = __fsub_rn(cb[3 * j + 1], cy);
      float dz = __fsub_rn(cb[3 * j + 2], cz);
      float d = __fadd_rn(__fadd_rn(__fmul_rn(dx, dx), __fmul_rn(dy, dy)), __fmul_rn(dz, dz));
      bool in = (d <= 0.25f);
      ull m = __ballot(in);
      if (in) {
        int pos = cnt + __popcll(m & ((1ull << lane) - 1ull));
        if (pos < K_) sgidx[wid][pos] = j;
      }
      if (!hasfirst && m) { first = base + (__ffsll((long long)m) - 1); hasfirst = true; }
      cnt += __popcll(m);
      if (cnt >= K_) break;
    }
    if (cnt < K_) {
      for (int p = cnt + lane; p < K_; p += 64) sgidx[wid][p] = first;
    }
  }
  if (lane < K_) gidx[g * K_ + lane] = sgidx[wid][lane];
  int l15 = lane & 15, r8 = (lane >> 4) * 8;
  const ushort_t* xb64 = xT + (size_t)b * N_ * 64;
  f32x4 acc[2][8];
#pragma unroll
  for (int nt = 0; nt < 8; ++nt) acc[0][nt] = (f32x4){0.f, 0.f, 0.f, 0.f};
#pragma unroll
  for (int kc = 0; kc < 2; ++kc) {
    bf16x8 cu = *(const bf16x8*)(xb64 + nf * 64 + kc * 32 + r8);
#pragma unroll
    for (int nt = 0; nt < 8; ++nt) {
      bf16x8 bf = *(const bf16x8*)(Bpd + ((nt * 2 + kc) * 64 + lane) * 8);
      acc[0][nt] = __builtin_amdgcn_mfma_f32_16x16x32_bf16(cu, bf, acc[0][nt], 0, 0, 0);
    }
  }
#pragma unroll
  for (int nt = 0; nt < 8; ++nt) acc[1][nt] = acc[0][nt];
  int gi0 = sgidx[wid][l15];
  int gi1 = sgidx[wid][16 + l15];
#pragma unroll
  for (int kc = 0; kc < 2; ++kc) {
    bf16x8 af0 = *(const bf16x8*)(xb64 + (size_t)gi0 * 64 + kc * 32 + r8);
    bf16x8 af1 = *(const bf16x8*)(xb64 + (size_t)gi1 * 64 + kc * 32 + r8);
#pragma unroll
    for (int nt = 0; nt < 8; ++nt) {
      bf16x8 bf = *(const bf16x8*)(Bp1 + ((nt * 2 + kc) * 64 + lane) * 8);
      acc[0][nt] = __builtin_amdgcn_mfma_f32_16x16x32_bf16(af0, bf, acc[0][nt], 0, 0, 0);
      acc[1][nt] = __builtin_amdgcn_mfma_f32_16x16x32_bf16(af1, bf, acc[1][nt], 0, 0, 0);
    }
  }
#pragma unroll
  for (int nt = 0; nt < 8; ++nt) {
    float s = 0.f, q = 0.f;
#pragma unroll
    for (int mt = 0; mt < 2; ++mt)
#pragma unroll
      for (int r = 0; r < 4; ++r) { float a = acc[mt][nt][r]; s += a; q = fmaf(a, a, q); }
    s += __shfl_xor(s, 16, 64); s += __shfl_xor(s, 32, 64);
    q += __shfl_xor(q, 16, 64); q += __shfl_xor(q, 32, 64);
    if (lane < 16) {
      int o = nt * 16 + lane;
      psum[o * G_ + g] = s; psq[o * G_ + g] = q;
    }
  }
}

// ---------------- BN finalize (bn1): per-channel mean/var -> scale/shift ----------
__global__ __launch_bounds__(256) void bn_finalize(const float* __restrict__ psum,
    const float* __restrict__ psq, const float* __restrict__ gamma,
    const float* __restrict__ beta, float* __restrict__ bnp) {
  int o = blockIdx.x, tid = threadIdx.x;
  double s = 0.0, q = 0.0;
  for (int g = tid; g < G_; g += 256) { s += (double)psum[o * G_ + g]; q += (double)psq[o * G_ + g]; }
  __shared__ double ss[256], qq[256];
  ss[tid] = s; qq[tid] = q; __syncthreads();
  for (int off = 128; off > 0; off >>= 1) {
    if (tid < off) { ss[tid] += ss[tid + off]; qq[tid] += qq[tid + off]; }
    __syncthreads();
  }
  if (tid == 0) {
    double n = 262144.0;
    double mean = ss[0] / n, var = qq[0] / n - mean * mean;
    float scv = (float)((double)gamma[o] / sqrt(var + 1e-5));
    bnp[2 * o] = scv;
    bnp[2 * o + 1] = (float)((double)beta[o] - mean * (double)scv);
  }
}

// ---------------- GEMM2 (MFMA bf16): recompute h1, W2 @ relu(bn1); o-major stats --
__global__ __launch_bounds__(256) void gemm2_kernel(const ushort_t* __restrict__ xT,
    const int* __restrict__ fidx, const int* __restrict__ gidx,
    const ushort_t* __restrict__ Bp1, const ushort_t* __restrict__ Bpd,
    const ushort_t* __restrict__ Bp2, const float* __restrict__ bnp1,
    float* __restrict__ psum, float* __restrict__ psq,
    float* __restrict__ hmax, float* __restrict__ hmin) {
  __shared__ ushort_t actT[4][32 * ATS];
  int tid = threadIdx.x;
  int lane = tid & 63, wid = tid >> 6;
  int g = __builtin_amdgcn_readfirstlane(blockIdx.x * 4 + wid);
  int b = g >> 9;
  int l15 = lane & 15, r8 = (lane >> 4) * 8;
  const ushort_t* xb64 = xT + (size_t)b * N_ * 64;
  int nf = fidx[g];
  f32x4 acc[2][8];
#pragma unroll
  for (int nt = 0; nt < 8; ++nt) acc[0][nt] = (f32x4){0.f, 0.f, 0.f, 0.f};
#pragma unroll
  for (int kc = 0; kc < 2; ++kc) {
    bf16x8 cu = *(const bf16x8*)(xb64 + nf * 64 + kc * 32 + r8);
#pragma unroll
    for (int nt = 0; nt < 8; ++nt) {
      bf16x8 bf = *(const bf16x8*)(Bpd + ((nt * 2 + kc) * 64 + lane) * 8);
      acc[0][nt] = __builtin_amdgcn_mfma_f32_16x16x32_bf16(cu, bf, acc[0][nt], 0, 0, 0);
    }
  }
#pragma unroll
  for (int nt = 0; nt < 8; ++nt) acc[1][nt] = acc[0][nt];
  int gi0 = gidx[g * K_ + l15];
  int gi1 = gidx[g * K_ + 16 + l15];
#pragma unroll
  for (int kc = 0; kc < 2; ++kc) {
    bf16x8 af0 = *(const bf16x8*)(xb64 + (size_t)gi0 * 64 + kc * 32 + r8);
    bf16x8 af1 = *(const bf16x8*)(xb64 + (size_t)gi1 * 64 + kc * 32 + r8);
#pragma unroll
    for (int nt = 0; nt < 8; ++nt) {
      bf16x8 bf = *(const bf16x8*)(Bp1 + ((nt * 2 + kc) * 64 + lane) * 8);
      acc[0][nt] = __builtin_amdgcn_mfma_f32_16x16x32_bf16(af0, bf, acc[0][nt], 0, 0, 0);
      acc[1][nt] = __builtin_amdgcn_mfma_f32_16x16x32_bf16(af1, bf, acc[1][nt], 0, 0, 0);
    }
  }
  float s1v[8], t1v[8];
#pragma unroll
  for (int nt = 0; nt < 8; ++nt) {
    int o = nt * 16 + l15;
    s1v[nt] = bnp1[2 * o]; t1v[nt] = bnp1[2 * o + 1];
  }
  ushort_t* aw = actT[wid];
#pragma unroll
  for (int mt = 0; mt < 2; ++mt)
#pragma unroll
    for (int r = 0; r < 4; ++r) {
      int k = mt * 16 + (lane >> 4) * 4 + r;
#pragma unroll
      for (int nt = 0; nt < 8; ++nt) {
        float a = fmaxf(fmaf(acc[mt][nt][r], s1v[nt], t1v[nt]), 0.f);
        aw[k * ATS + nt * 16 + l15] = (ushort_t)bf16b(a);
      }
    }
  f32x4 acc2[2][8];
#pragma unroll
  for (int mt = 0; mt < 2; ++mt)
#pragma unroll
    for (int nt = 0; nt < 8; ++nt) acc2[mt][nt] = (f32x4){0.f, 0.f, 0.f, 0.f};
#pragma unroll
  for (int kc = 0; kc < 4; ++kc) {
    bf16x8 afrag[2];
#pragma unroll
    for (int mt = 0; mt < 2; ++mt)
      afrag[mt] = *(const bf16x8*)(aw + (mt * 16 + l15) * ATS + kc * 32 + r8);
#pragma unroll
    for (int nt = 0; nt < 8; ++nt) {
      bf16x8 bfrag = *(const bf16x8*)(Bp2 + ((nt * 4 + kc) * 64 + lane) * 8);
      acc2[0][nt] = __builtin_amdgcn_mfma_f32_16x16x32_bf16(afrag[0], bfrag, acc2[0][nt], 0, 0, 0);
      acc2[1][nt] = __builtin_amdgcn_mfma_f32_16x16x32_bf16(afrag[1], bfrag, acc2[1][nt], 0, 0, 0);
    }
  }
#pragma unroll
  for (int nt = 0; nt < 8; ++nt) {
    float s = 0.f, q = 0.f, mx = -1e30f, mn = 1e30f;
#pragma unroll
    for (int mt = 0; mt < 2; ++mt)
#pragma unroll
      for (int r = 0; r < 4; ++r) {
        float a = acc2[mt][nt][r];
        s += a; q = fmaf(a, a, q); mx = fmaxf(mx, a); mn = fminf(mn, a);
      }
    s += __shfl_xor(s, 16, 64); s += __shfl_xor(s, 32, 64);
    q += __shfl_xor(q, 16, 64); q += __shfl_xor(q, 32, 64);
    mx = fmaxf(mx, __shfl_xor(mx, 16, 64)); mx = fmaxf(mx, __shfl_xor(mx, 32, 64));
    mn = fminf(mn, __shfl_xor(mn, 16, 64)); mn = fminf(mn, __shfl_xor(mn, 32, 64));
    if (lane < 16) {
      int o = nt * 16 + lane;
      psum[o * G_ + g] = s; psq[o * G_ + g] = q;
      hmax[o * G_ + g] = mx; hmin[o * G_ + g] = mn;
    }
  }
}

// ---------------- bn2 + pool fused: per-channel stats -> direct output -----------
__global__ __launch_bounds__(256) void bn2pool_kernel(const float* __restrict__ psum,
    const float* __restrict__ psq, const float* __restrict__ gamma,
    const float* __restrict__ beta, const float* __restrict__ hmax,
    const float* __restrict__ hmin, float* __restrict__ out) {
  int o = blockIdx.x, tid = threadIdx.x;
  double s = 0.0, q = 0.0;
  for (int g = tid; g < G_; g += 256) { s += (double)psum[o * G_ + g]; q += (double)psq[o * G_ + g]; }
  __shared__ double ss[256], qq[256];
  __shared__ float sb[2];
  ss[tid] = s; qq[tid] = q; __syncthreads();
  for (int off = 128; off > 0; off >>= 1) {
    if (tid < off) { ss[tid] += ss[tid + off]; qq[tid] += qq[tid + off]; }
    __syncthreads();
  }
  if (tid == 0) {
    double n = 262144.0;
    double mean = ss[0] / n, var = qq[0] / n - mean * mean;
    float scv = (float)((double)gamma[o] / sqrt(var + 1e-5));
    sb[0] = scv;
    sb[1] = (float)((double)beta[o] - mean * (double)scv);
  }
  __syncthreads();
  float scv = sb[0], tf = sb[1];
  for (int g = tid; g < G_; g += 256) {
    float v = (scv >= 0.f) ? hmax[o * G_ + g] : hmin[o * G_ + g];
    int b = g >> 9, s2 = g & 511;
    out[((b << 7) + o) * 512 + s2] = fmaxf(fmaf(scv, v, tf), 0.f);
  }
}

extern "C" void kernel_launch(void* const* d_in, const int* in_sizes, int n_in,
                              void* d_out, int out_size, void* d_ws, size_t ws_size,
                              hipStream_t stream) {
  const float* x      = (const float*)d_in[0];
  const float* coords = (const float*)d_in[1];
  const float* W1     = (const float*)d_in[2];
  const float* W2     = (const float*)d_in[3];
  const float* gamma1 = (const float*)d_in[4];
  const float* beta1  = (const float*)d_in[5];
  const float* gamma2 = (const float*)d_in[6];
  const float* beta2  = (const float*)d_in[7];
  float* out = (float*)d_out;
  char* ws = (char*)d_ws;
  float* psum1 = (float*)(ws);                    // 4 MB each
  float* psq1  = (float*)(ws + 4194304);
  float* psum2 = (float*)(ws + 8388608);
  float* psq2  = (float*)(ws + 12582912);
  float* hmax  = (float*)(ws + 16777216);
  float* hmin  = (float*)(ws + 20971520);
  ushort_t* xT = (ushort_t*)(ws + 25165824);      // 4 MB  xT[b][n][c] bf16
  ushort_t* Bp1 = (ushort_t*)(ws + 29360128);     // 16 KB
  ushort_t* Bpd = (ushort_t*)(ws + 29376512);     // 16 KB
  ushort_t* Bp2 = (ushort_t*)(ws + 29392896);     // 32 KB
  float* bnp1  = (float*)(ws + 29425664);
  int* fidx    = (int*)(ws + 29427712);           // 32 KB
  int* gidx    = (int*)(ws + 29460480);           // 1 MB, end ~30.5 MB

  front_kernel<<<592, 256, 0, stream>>>(coords, x, W1, W2, fidx, out, xT, Bp1, Bpd, Bp2);
  gemm1_kernel<<<2048, 256, 0, stream>>>(xT, coords, fidx, Bp1, Bpd, gidx, psum1, psq1);
  bn_finalize<<<128, 256, 0, stream>>>(psum1, psq1, gamma1, beta1, bnp1);
  gemm2_kernel<<<2048, 256, 0, stream>>>(xT, fidx, gidx, Bp1, Bpd, Bp2, bnp1,
                                         psum2, psq2, hmax, hmin);
  bn2pool_kernel<<<128, 256, 0, stream>>>(psum2, psq2, gamma2, beta2, hmax, hmin,
                                          out + 24576);
}

// Round 17
// 348.720 us; speedup vs baseline: 1.5319x; 1.5319x over previous
//
#include <hip/hip_runtime.h>
#include <cstdint>

typedef unsigned int uint;
typedef unsigned short ushort_t;
typedef unsigned long long ull;
typedef __attribute__((ext_vector_type(8))) short bf16x8;
typedef __attribute__((ext_vector_type(4))) float f32x4;
typedef __attribute__((ext_vector_type(2))) float f32x2;

#define B_   16
#define N_   2048
#define S_   512
#define G_   8192       // B_*S_
#define DIN  64
#define DOUT 128
#define K_   32
#define ATS  136        // gemm2 actT row stride (bf16)

__device__ __forceinline__ uint bf16b(float f) {
  uint u = __float_as_uint(f);
  return (u + 0x7fffu + ((u >> 16) & 1u)) >> 16;
}
__device__ __forceinline__ float bf2f(uint b) { return __uint_as_float(b << 16); }

template<int CTRL, int RM>
__device__ __forceinline__ float dpp_fmax_step(float x) {
  float y = __uint_as_float((uint)__builtin_amdgcn_update_dpp(
      (int)__float_as_uint(x), (int)__float_as_uint(x), CTRL, RM, 0xf, true));
  return fmaxf(x, y);   // bound_ctrl zero-fill: dists >= 0 -> identity for max
}

// ---------------- front: fps (blocks 0-15, FROZEN ~229us) | txp | prep ------------
// FPS: 4 waves x 8 pts/lane, exact fp32. pk-pair update; value-only DPP max ->
// ballot/ffs resolve; lane0 ships 8B key; post-barrier 4 keys + 12 speculative
// coord reads overlap the key tree. Ref scan emits PRE-update far (idx[0]==0).
__global__ __launch_bounds__(256) void front_kernel(const float* __restrict__ coords,
    const float* __restrict__ x, const float* __restrict__ W1,
    const float* __restrict__ W2, int* __restrict__ fidx,
    float* __restrict__ out_xyz, ushort_t* __restrict__ xT,
    ushort_t* __restrict__ Bp1, ushort_t* __restrict__ Bpd,
    ushort_t* __restrict__ Bp2) {
  int blk = blockIdx.x;
  int tid = threadIdx.x;
  if (blk < 16) {
    int b = blk;
    const float* cb = coords + (size_t)b * (N_ * 3);
    __shared__ float sptx[N_], spty[N_], sptz[N_];
    __shared__ ull   skey[2][4];
    __shared__ int   sfar[S_];
    int lane = tid & 63, wid = tid >> 6;
    for (int j = tid; j < N_; j += 256) {
      sptx[j] = cb[3 * j]; spty[j] = cb[3 * j + 1]; sptz[j] = cb[3 * j + 2];
    }
    f32x2 px[4], py[4], pz[4], dist[4];
    int j0 = tid * 8;
#pragma unroll
    for (int p = 0; p < 4; ++p) {
      int j = j0 + 2 * p;
      px[p].x = cb[3 * j];     py[p].x = cb[3 * j + 1]; pz[p].x = cb[3 * j + 2];
      px[p].y = cb[3 * j + 3]; py[p].y = cb[3 * j + 4]; pz[p].y = cb[3 * j + 5];
      dist[p].x = 1e10f; dist[p].y = 1e10f;
    }
    float cx = cb[0], cy = cb[1], cz = cb[2];
    uint far = 0;
    __syncthreads();
    for (int s = 0; s < S_; ++s) {
      if (tid == 0) sfar[s] = (int)far;          // PRE-update far (matches jax scan)
      f32x2 c2x = {cx, cx}, c2y = {cy, cy}, c2z = {cz, cz};
      float bestv = -1.f; uint bestloc = 0;
#pragma unroll
      for (int p = 0; p < 4; ++p) {
        f32x2 dx, dy, dz, qx, qy, qz, s1, s2;
        asm("v_pk_add_f32 %0, %1, %2 neg_lo:[0,1] neg_hi:[0,1]" : "=v"(dx) : "v"(px[p]), "v"(c2x));
        asm("v_pk_add_f32 %0, %1, %2 neg_lo:[0,1] neg_hi:[0,1]" : "=v"(dy) : "v"(py[p]), "v"(c2y));
        asm("v_pk_add_f32 %0, %1, %2 neg_lo:[0,1] neg_hi:[0,1]" : "=v"(dz) : "v"(pz[p]), "v"(c2z));
        asm("v_pk_mul_f32 %0, %1, %1" : "=v"(qx) : "v"(dx));
        asm("v_pk_mul_f32 %0, %1, %1" : "=v"(qy) : "v"(dy));
        asm("v_pk_mul_f32 %0, %1, %1" : "=v"(qz) : "v"(dz));
        asm("v_pk_add_f32 %0, %1, %2" : "=v"(s1) : "v"(qx), "v"(qy));
        asm("v_pk_add_f32 %0, %1, %2" : "=v"(s2) : "v"(s1), "v"(qz));
        float n0 = fminf(dist[p].x, s2.x);
        float n1 = fminf(dist[p].y, s2.y);
        dist[p].x = n0; dist[p].y = n1;
        bool g0 = n0 > bestv; bestv = g0 ? n0 : bestv; bestloc = g0 ? (uint)(2 * p) : bestloc;
        bool g1 = n1 > bestv; bestv = g1 ? n1 : bestv; bestloc = g1 ? (uint)(2 * p + 1) : bestloc;
      }
      // wave64 value-max (6 dpp+max, lands full in lane 63)
      float m = bestv;
      m = dpp_fmax_step<0x111, 0xf>(m);   // row_shr:1
      m = dpp_fmax_step<0x112, 0xf>(m);   // row_shr:2
      m = dpp_fmax_step<0x114, 0xf>(m);   // row_shr:4
      m = dpp_fmax_step<0x118, 0xf>(m);   // row_shr:8
      m = dpp_fmax_step<0x142, 0xa>(m);   // row_bcast:15 -> rows 1,3
      m = dpp_fmax_step<0x143, 0xc>(m);   // row_bcast:31 -> rows 2,3
      float wmax = __uint_as_float((uint)__builtin_amdgcn_readlane((int)__float_as_uint(m), 63));
      ull mask = __ballot(bestv == wmax);
      int wl = __ffsll((long long)mask) - 1;            // first lane = smallest j
      uint loc = (uint)__builtin_amdgcn_readlane((int)bestloc, wl);
      uint jg = (uint)(((wid << 6) + wl) * 8) + loc;    // wave-winner global index
      int pb = s & 1;
      if (lane == 0) skey[pb][wid] = ((ull)__float_as_uint(wmax) << 32) | (ull)(~jg);
      __syncthreads();                                  // lgkm-only barrier
      ull k0 = skey[pb][0], k1 = skey[pb][1], k2 = skey[pb][2], k3 = skey[pb][3];
      uint w0 = ~(uint)k0, w1 = ~(uint)k1, w2 = ~(uint)k2, w3 = ~(uint)k3;
      float x0 = sptx[w0], y0 = spty[w0], z0 = sptz[w0];   // 12 speculative broadcast
      float x1 = sptx[w1], y1 = spty[w1], z1 = sptz[w1];   // reads, overlap the tree
      float x2 = sptx[w2], y2 = spty[w2], z2 = sptz[w2];
      float x3 = sptx[w3], y3 = spty[w3], z3 = sptz[w3];
      bool t01 = k0 > k1, t23 = k2 > k3;
      ull ka = t01 ? k0 : k1;  float xa = t01 ? x0 : x1, ya = t01 ? y0 : y1, za = t01 ? z0 : z1;
      ull kb = t23 ? k2 : k3;  float xb = t23 ? x2 : x3, yb = t23 ? y2 : y3, zb = t23 ? z2 : z3;
      bool tw = ka > kb;
      far = ~(uint)(tw ? ka : kb);
      cx = tw ? xa : xb; cy = tw ? ya : yb; cz = tw ? za : zb;
    }
    __syncthreads();
    for (int s2 = tid; s2 < S_; s2 += 256) {
      int f = sfar[s2];
      fidx[b * S_ + s2] = f;
      int o = (b * S_ + s2) * 3;
      out_xyz[o] = sptx[f]; out_xyz[o + 1] = spty[f]; out_xyz[o + 2] = sptz[f];
    }
  } else if (blk < 528) {
    // ------------------ txp: x[b][c][n] fp32 -> xT[b][n][c] bf16 ------------------
    __shared__ float tile[64][65];
    int blk2 = blk - 16;
    int b = blk2 >> 5;            // 16 b x 32 n-tiles
    int n0 = (blk2 & 31) * 64;
    int nn = tid & 63, c4 = tid >> 6;
    const float* xb = x + (size_t)b * (DIN * N_);
#pragma unroll
    for (int i = 0; i < 16; ++i) {
      int c = c4 * 16 + i;
      tile[nn][c] = xb[(size_t)c * N_ + n0 + nn];   // coalesced along n
    }
    __syncthreads();
#pragma unroll
    for (int i = 0; i < 16; ++i) {
      int n = c4 * 16 + i;
      xT[((size_t)b * N_ + n0 + n) * 64 + nn] = (ushort_t)bf16b(tile[n][nn]);  // coalesced along c
    }
  } else {
    // ------------------ prep: B-fragment packs for both GEMMs ------------------
    int i = (blk - 528) * 256 + tid;   // 16384
    int j2 = i & 7, l = (i >> 3) & 63;
    {
      int kc = (i >> 9) & 3, nt = i >> 11;
      int o2 = nt * 16 + (l & 15);
      int c2 = kc * 32 + ((l >> 4) * 8) + j2;
      Bp2[i] = (ushort_t)bf16b(W2[o2 * 128 + c2]);
    }
    if (i < 8192) {
      int kc = (i >> 9) & 1, nt = (i >> 10) & 7;
      int o2 = nt * 16 + (l & 15);
      int c2 = kc * 32 + ((l >> 4) * 8) + j2;
      float wa = W1[o2 * 128 + c2];
      float wb = W1[o2 * 128 + 64 + c2];
      Bp1[i] = (ushort_t)bf16b(wa);
      Bpd[i] = (ushort_t)bf16b(wb - wa);
    }
  }
}

// ---------------- GEMM1 (MFMA bf16) + inline ball query: stats only --------------
__global__ __launch_bounds__(256) void gemm1_kernel(const ushort_t* __restrict__ xT,
    const float* __restrict__ coords, const int* __restrict__ fidx,
    const ushort_t* __restrict__ Bp1, const ushort_t* __restrict__ Bpd,
    int* __restrict__ gidx, float* __restrict__ psum, float* __restrict__ psq) {
  __shared__ int sgidx[4][K_];
  int tid = threadIdx.x;
  int lane = tid & 63, wid = tid >> 6;
  int g = __builtin_amdgcn_readfirstlane(blockIdx.x * 4 + wid);
  int b = g >> 9;
  const float* cb = coords + (size_t)b * (N_ * 3);
  int nf = fidx[g];
  {
    float cx = cb[3 * nf], cy = cb[3 * nf + 1], cz = cb[3 * nf + 2];
    int cnt = 0, first = 0;
    bool hasfirst = false;
    for (int base = 0; base < N_; base += 64) {
      int j = base + lane;
      float dx = __fsub_rn(cb[3 * j], cx);
      float dy = __fsub_rn(cb[3 * j + 1], cy);
      float dz = __fsub_rn(cb[3 * j + 2], cz);
      float d = __fadd_rn(__fadd_rn(__fmul_rn(dx, dx), __fmul_rn(dy, dy)), __fmul_rn(dz, dz));
      bool in = (d <= 0.25f);
      ull m = __ballot(in);
      if (in) {
        int pos = cnt + __popcll(m & ((1ull << lane) - 1ull));
        if (pos < K_) sgidx[wid][pos] = j;
      }
      if (!hasfirst && m) { first = base + (__ffsll((long long)m) - 1); hasfirst = true; }
      cnt += __popcll(m);
      if (cnt >= K_) break;
    }
    if (cnt < K_) {
      for (int p = cnt + lane; p < K_; p += 64) sgidx[wid][p] = first;
    }
  }
  if (lane < K_) gidx[g * K_ + lane] = sgidx[wid][lane];
  int l15 = lane & 15, r8 = (lane >> 4) * 8;
  const ushort_t* xb64 = xT + (size_t)b * N_ * 64;
  f32x4 acc[2][8];
#pragma unroll
  for (int nt = 0; nt < 8; ++nt) acc[0][nt] = (f32x4){0.f, 0.f, 0.f, 0.f};
#pragma unroll
  for (int kc = 0; kc < 2; ++kc) {
    bf16x8 cu = *(const bf16x8*)(xb64 + nf * 64 + kc * 32 + r8);
#pragma unroll
    for (int nt = 0; nt < 8; ++nt) {
      bf16x8 bf = *(const bf16x8*)(Bpd + ((nt * 2 + kc) * 64 + lane) * 8);
      acc[0][nt] = __builtin_amdgcn_mfma_f32_16x16x32_bf16(cu, bf, acc[0][nt], 0, 0, 0);
    }
  }
#pragma unroll
  for (int nt = 0; nt < 8; ++nt) acc[1][nt] = acc[0][nt];
  int gi0 = sgidx[wid][l15];
  int gi1 = sgidx[wid][16 + l15];
#pragma unroll
  for (int kc = 0; kc < 2; ++kc) {
    bf16x8 af0 = *(const bf16x8*)(xb64 + (size_t)gi0 * 64 + kc * 32 + r8);
    bf16x8 af1 = *(const bf16x8*)(xb64 + (size_t)gi1 * 64 + kc * 32 + r8);
#pragma unroll
    for (int nt = 0; nt < 8; ++nt) {
      bf16x8 bf = *(const bf16x8*)(Bp1 + ((nt * 2 + kc) * 64 + lane) * 8);
      acc[0][nt] = __builtin_amdgcn_mfma_f32_16x16x32_bf16(af0, bf, acc[0][nt], 0, 0, 0);
      acc[1][nt] = __builtin_amdgcn_mfma_f32_16x16x32_bf16(af1, bf, acc[1][nt], 0, 0, 0);
    }
  }
#pragma unroll
  for (int nt = 0; nt < 8; ++nt) {
    float s = 0.f, q = 0.f;
#pragma unroll
    for (int mt = 0; mt < 2; ++mt)
#pragma unroll
      for (int r = 0; r < 4; ++r) { float a = acc[mt][nt][r]; s += a; q = fmaf(a, a, q); }
    s += __shfl_xor(s, 16, 64); s += __shfl_xor(s, 32, 64);
    q += __shfl_xor(q, 16, 64); q += __shfl_xor(q, 32, 64);
    if (lane < 16) {
      int o = nt * 16 + lane;
      psum[o * G_ + g] = s; psq[o * G_ + g] = q;
    }
  }
}

// ---------------- BN finalize (bn1): per-channel mean/var -> scale/shift ----------
__global__ __launch_bounds__(256) void bn_finalize(const float* __restrict__ psum,
    const float* __restrict__ psq, const float* __restrict__ gamma,
    const float* __restrict__ beta, float* __restrict__ bnp) {
  int o = blockIdx.x, tid = threadIdx.x;
  double s = 0.0, q = 0.0;
  for (int g = tid; g < G_; g += 256) { s += (double)psum[o * G_ + g]; q += (double)psq[o * G_ + g]; }
  __shared__ double ss[256], qq[256];
  ss[tid] = s; qq[tid] = q; __syncthreads();
  for (int off = 128; off > 0; off >>= 1) {
    if (tid < off) { ss[tid] += ss[tid + off]; qq[tid] += qq[tid + off]; }
    __syncthreads();
  }
  if (tid == 0) {
    double n = 262144.0;
    double mean = ss[0] / n, var = qq[0] / n - mean * mean;
    float scv = (float)((double)gamma[o] / sqrt(var + 1e-5));
    bnp[2 * o] = scv;
    bnp[2 * o + 1] = (float)((double)beta[o] - mean * (double)scv);
  }
}

// ---------------- GEMM2 (MFMA bf16): recompute h1 from xT, then W2 @ relu(bn1) ----
__global__ __launch_bounds__(256) void gemm2_kernel(const ushort_t* __restrict__ xT,
    const int* __restrict__ fidx, const int* __restrict__ gidx,
    const ushort_t* __restrict__ Bp1, const ushort_t* __restrict__ Bpd,
    const ushort_t* __restrict__ Bp2, const float* __restrict__ bnp1,
    float* __restrict__ psum, float* __restrict__ psq,
    float* __restrict__ hmax, float* __restrict__ hmin) {
  __shared__ ushort_t actT[4][32 * ATS];
  int tid = threadIdx.x;
  int lane = tid & 63, wid = tid >> 6;
  int g = __builtin_amdgcn_readfirstlane(blockIdx.x * 4 + wid);
  int b = g >> 9;
  int l15 = lane & 15, r8 = (lane >> 4) * 8;
  const ushort_t* xb64 = xT + (size_t)b * N_ * 64;
  int nf = fidx[g];
  f32x4 acc[2][8];
#pragma unroll
  for (int nt = 0; nt < 8; ++nt) acc[0][nt] = (f32x4){0.f, 0.f, 0.f, 0.f};
#pragma unroll
  for (int kc = 0; kc < 2; ++kc) {
    bf16x8 cu = *(const bf16x8*)(xb64 + nf * 64 + kc * 32 + r8);
#pragma unroll
    for (int nt = 0; nt < 8; ++nt) {
      bf16x8 bf = *(const bf16x8*)(Bpd + ((nt * 2 + kc) * 64 + lane) * 8);
      acc[0][nt] = __builtin_amdgcn_mfma_f32_16x16x32_bf16(cu, bf, acc[0][nt], 0, 0, 0);
    }
  }
#pragma unroll
  for (int nt = 0; nt < 8; ++nt) acc[1][nt] = acc[0][nt];
  int gi0 = gidx[g * K_ + l15];
  int gi1 = gidx[g * K_ + 16 + l15];
#pragma unroll
  for (int kc = 0; kc < 2; ++kc) {
    bf16x8 af0 = *(const bf16x8*)(xb64 + (size_t)gi0 * 64 + kc * 32 + r8);
    bf16x8 af1 = *(const bf16x8*)(xb64 + (size_t)gi1 * 64 + kc * 32 + r8);
#pragma unroll
    for (int nt = 0; nt < 8; ++nt) {
      bf16x8 bf = *(const bf16x8*)(Bp1 + ((nt * 2 + kc) * 64 + lane) * 8);
      acc[0][nt] = __builtin_amdgcn_mfma_f32_16x16x32_bf16(af0, bf, acc[0][nt], 0, 0, 0);
      acc[1][nt] = __builtin_amdgcn_mfma_f32_16x16x32_bf16(af1, bf, acc[1][nt], 0, 0, 0);
    }
  }
  float s1v[8], t1v[8];
#pragma unroll
  for (int nt = 0; nt < 8; ++nt) {
    int o = nt * 16 + l15;
    s1v[nt] = bnp1[2 * o]; t1v[nt] = bnp1[2 * o + 1];
  }
  ushort_t* aw = actT[wid];
#pragma unroll
  for (int mt = 0; mt < 2; ++mt)
#pragma unroll
    for (int r = 0; r < 4; ++r) {
      int k = mt * 16 + (lane >> 4) * 4 + r;
#pragma unroll
      for (int nt = 0; nt < 8; ++nt) {
        float a = fmaxf(fmaf(acc[mt][nt][r], s1v[nt], t1v[nt]), 0.f);
        aw[k * ATS + nt * 16 + l15] = (ushort_t)bf16b(a);
      }
    }
  f32x4 acc2[2][8];
#pragma unroll
  for (int mt = 0; mt < 2; ++mt)
#pragma unroll
    for (int nt = 0; nt < 8; ++nt) acc2[mt][nt] = (f32x4){0.f, 0.f, 0.f, 0.f};
#pragma unroll
  for (int kc = 0; kc < 4; ++kc) {
    bf16x8 afrag[2];
#pragma unroll
    for (int mt = 0; mt < 2; ++mt)
      afrag[mt] = *(const bf16x8*)(aw + (mt * 16 + l15) * ATS + kc * 32 + r8);
#pragma unroll
    for (int nt = 0; nt < 8; ++nt) {
      bf16x8 bfrag = *(const bf16x8*)(Bp2 + ((nt * 4 + kc) * 64 + lane) * 8);
      acc2[0][nt] = __builtin_amdgcn_mfma_f32_16x16x32_bf16(afrag[0], bfrag, acc2[0][nt], 0, 0, 0);
      acc2[1][nt] = __builtin_amdgcn_mfma_f32_16x16x32_bf16(afrag[1], bfrag, acc2[1][nt], 0, 0, 0);
    }
  }
#pragma unroll
  for (int nt = 0; nt < 8; ++nt) {
    float s = 0.f, q = 0.f, mx = -1e30f, mn = 1e30f;
#pragma unroll
    for (int mt = 0; mt < 2; ++mt)
#pragma unroll
      for (int r = 0; r < 4; ++r) {
        float a = acc2[mt][nt][r];
        s += a; q = fmaf(a, a, q); mx = fmaxf(mx, a); mn = fminf(mn, a);
      }
    s += __shfl_xor(s, 16, 64); s += __shfl_xor(s, 32, 64);
    q += __shfl_xor(q, 16, 64); q += __shfl_xor(q, 32, 64);
    mx = fmaxf(mx, __shfl_xor(mx, 16, 64)); mx = fmaxf(mx, __shfl_xor(mx, 32, 64));
    mn = fminf(mn, __shfl_xor(mn, 16, 64)); mn = fminf(mn, __shfl_xor(mn, 32, 64));
    if (lane < 16) {
      int o = nt * 16 + lane;
      psum[o * G_ + g] = s; psq[o * G_ + g] = q;
      hmax[o * G_ + g] = mx; hmin[o * G_ + g] = mn;
    }
  }
}

// ---------------- bn2 + pool fused: per-channel stats -> direct output -----------
__global__ __launch_bounds__(256) void bn2pool_kernel(const float* __restrict__ psum,
    const float* __restrict__ psq, const float* __restrict__ gamma,
    const float* __restrict__ beta, const float* __restrict__ hmax,
    const float* __restrict__ hmin, float* __restrict__ out) {
  int o = blockIdx.x, tid = threadIdx.x;
  double s = 0.0, q = 0.0;
  for (int g = tid; g < G_; g += 256) { s += (double)psum[o * G_ + g]; q += (double)psq[o * G_ + g]; }
  __shared__ double ss[256], qq[256];
  __shared__ float sb[2];
  ss[tid] = s; qq[tid] = q; __syncthreads();
  for (int off = 128; off > 0; off >>= 1) {
    if (tid < off) { ss[tid] += ss[tid + off]; qq[tid] += qq[tid + off]; }
    __syncthreads();
  }
  if (tid == 0) {
    double n = 262144.0;
    double mean = ss[0] / n, var = qq[0] / n - mean * mean;
    float scv = (float)((double)gamma[o] / sqrt(var + 1e-5));
    sb[0] = scv;
    sb[1] = (float)((double)beta[o] - mean * (double)scv);
  }
  __syncthreads();
  float scv = sb[0], tf = sb[1];
  for (int g = tid; g < G_; g += 256) {
    float v = (scv >= 0.f) ? hmax[o * G_ + g] : hmin[o * G_ + g];
    int b = g >> 9, s2 = g & 511;
    out[((b << 7) + o) * 512 + s2] = fmaxf(fmaf(scv, v, tf), 0.f);
  }
}

extern "C" void kernel_launch(void* const* d_in, const int* in_sizes, int n_in,
                              void* d_out, int out_size, void* d_ws, size_t ws_size,
                              hipStream_t stream) {
  const float* x      = (const float*)d_in[0];
  const float* coords = (const float*)d_in[1];
  const float* W1     = (const float*)d_in[2];
  const float* W2     = (const float*)d_in[3];
  const float* gamma1 = (const float*)d_in[4];
  const float* beta1  = (const float*)d_in[5];
  const float* gamma2 = (const float*)d_in[6];
  const float* beta2  = (const float*)d_in[7];
  float* out = (float*)d_out;
  char* ws = (char*)d_ws;
  float* psum1 = (float*)(ws);                    // 4 MB each
  float* psq1  = (float*)(ws + 4194304);
  float* psum2 = (float*)(ws + 8388608);
  float* psq2  = (float*)(ws + 12582912);
  float* hmax  = (float*)(ws + 16777216);
  float* hmin  = (float*)(ws + 20971520);
  ushort_t* xT = (ushort_t*)(ws + 25165824);      // 4 MB  xT[b][n][c] bf16
  ushort_t* Bp1 = (ushort_t*)(ws + 29360128);     // 16 KB
  ushort_t* Bpd = (ushort_t*)(ws + 29376512);     // 16 KB
  ushort_t* Bp2 = (ushort_t*)(ws + 29392896);     // 32 KB
  float* bnp1  = (float*)(ws + 29425664);
  int* fidx    = (int*)(ws + 29427712);           // 32 KB
  int* gidx    = (int*)(ws + 29460480);           // 1 MB, end ~30.5 MB

  front_kernel<<<592, 256, 0, stream>>>(coords, x, W1, W2, fidx, out, xT, Bp1, Bpd, Bp2);
  gemm1_kernel<<<2048, 256, 0, stream>>>(xT, coords, fidx, Bp1, Bpd, gidx, psum1, psq1);
  bn_finalize<<<128, 256, 0, stream>>>(psum1, psq1, gamma1, beta1, bnp1);
  gemm2_kernel<<<2048, 256, 0, stream>>>(xT, fidx, gidx, Bp1, Bpd, Bp2, bnp1,
                                         psum2, psq2, hmax, hmin);
  bn2pool_kernel<<<128, 256, 0, stream>>>(psum2, psq2, gamma2, beta2, hmax, hmin,
                                          out + 24576);
}